// Round 11
// baseline (117.986 us; speedup 1.0000x reference)
//
#include <hip/hip_runtime.h>

// SepConv on sphere, round 11: ONE kernel, PERSISTENT pipelined blocks.
// Algebra (verified absmax 0.0 since R2): the chain
//   x -> *qw -> DISCO(K=4,9tap) -> depth-mix -> *qw -> DISCO(K=1,4tap) -> 1x1
// composes into one 5x5 clip/wrap stencil with per-(c,h) coefs
// C[c][25] = w_depth[c,:] . S[4][25] (144 composed taps per row), then a
// 32->64 pointwise GEMV.
//
// R11: 512 persistent blocks (2/CU, one generation), each pinned to XCD band
// bx&7 and grid-striding its band's (h,seg) tiles. Software pipeline:
//   - x-loads for tile t+1 issue right after tile t's stencil FMAs,
//   - tap-decode (chained global loads) for t+1 issues under tile t's GEMV.
// Attacks the cross-round invariant: every per-tile-workgroup variant sits
// at 38-45us with all pipes idle (launch/teardown + unhidden latency clumps).

#define H_    181
#define W_    360
#define CIN_  32
#define COUT_ 64
#define K_    4
#define NNZ_  9
#define NNZ1_ 4
#define HW_   (H_*W_)
#define NT_   (NNZ1_*K_*NNZ_)   // 144 composed taps per output row

__device__ __forceinline__ void tile_hs(int band, int t, int& h, int& seg) {
    h   = band * 23 + t / 6;
    seg = t - (t / 6) * 6;
}

__global__ __launch_bounds__(512, 4) void sepconv_persist(
    const float* __restrict__ x, const float* __restrict__ quad_w,
    const float* __restrict__ vals, const int* __restrict__ hi,
    const int* __restrict__ wi, const float* __restrict__ w_depth,
    const float* __restrict__ vals1, const int* __restrict__ hi1,
    const int* __restrict__ wi1, const float* __restrict__ w_point,
    const float* __restrict__ bias, float* __restrict__ out)
{
    const int bx     = blockIdx.x;
    const int band   = bx & 7;                   // XCD id; 23-row band
    const int within = bx >> 3;                  // 0..63 within band
    const int rows   = (band < 7) ? 23 : 20;     // 181 = 7*23 + 20
    const int nt     = rows * 6;                 // tiles in this band
    const int tid    = threadIdx.x;

    const int g = tid & 15;                      // 4-px group (stencil role)
    const int c = tid >> 4;                      // channel  (stencil role)
    const int j  = tid & 63;                     // px lane  (GEMV role)
    const int oh = tid >> 6;                     // o-eighth (GEMV role)

    __shared__ float Tval[NT_];
    __shared__ int   Tbin[NT_];
    __shared__ float S[K_][25];
    __shared__ float C[CIN_][25];
    __shared__ float zs[64][33];   // [px][ch]; <=2-way banks (free)

    // tap decode for row h -> Tval/Tbin (threads 0..143)
    auto decode = [&](int h) {
        if (tid < NT_) {
            const int a   = tid / 36;
            const int rem = tid - a * 36;
            const int k   = rem / 9;
            const int jj  = rem - k * 9;
            const int e1  = h * NNZ1_ + a;
            const int m   = hi1[e1];
            const int w1  = wi1[e1];
            const int d1  = (w1 == 1) ? 1 : ((w1 == 0) ? 0 : -1);
            const int e   = (k * H_ + m) * NNZ_ + jj;
            const int r   = hi[e];
            const int ww  = wi[e];
            const int d   = (ww == 1) ? 1 : ((ww == 0) ? 0 : -1);
            Tval[tid] = vals1[e1] * quad_w[m] * vals[e] * quad_w[r];
            Tbin[tid] = (r - h + 2) * 5 + (d1 + d + 2);   // in [0,25)
        }
    };
    auto build_S = [&]() {              // parallel read-only scans
        if (tid < K_ * 25) {
            const int k   = tid / 25;
            const int bin = tid - k * 25;
            float s = 0.f;
            #pragma unroll
            for (int a = 0; a < NNZ1_; ++a)
                #pragma unroll
                for (int jj = 0; jj < NNZ_; ++jj) {
                    const int t2 = a * 36 + k * 9 + jj;
                    if (Tbin[t2] == bin) s += Tval[t2];
                }
            S[k][bin] = s;
        }
    };
    auto build_C = [&]() {
        for (int i = tid; i < CIN_ * 25; i += 512) {
            const int cc = i / 25, bin = i - cc * 25;
            float acc = 0.f;
            #pragma unroll
            for (int k = 0; k < K_; ++k)
                acc += w_depth[cc * K_ + k] * S[k][bin];
            C[cc][bin] = acc;
        }
    };
    auto load_x = [&](int h, int seg, float4* L, bool& act) {
        const int pxn = (seg == 5) ? 40 : 64;
        act = (g < (pxn >> 2));
        if (act) {
            const int bw = seg * 64 + g * 4;
            const int cA = (bw + W_ - 4) % W_;
            const int cB = bw;
            const int cC = (bw + 4) % W_;
            const float* xc = x + c * HW_;
            #pragma unroll
            for (int rb = 0; rb < 5; ++rb) {
                int r = h - 2 + rb;
                r = (r < 0) ? 0 : ((r > H_ - 1) ? H_ - 1 : r);
                const float* xr = xc + r * W_;
                L[rb * 3 + 0] = *(const float4*)(xr + cA);
                L[rb * 3 + 1] = *(const float4*)(xr + cB);
                L[rb * 3 + 2] = *(const float4*)(xr + cC);
            }
        }
    };

    // ---- preamble: tile0 x-prefetch overlaps tile0 prologue ----------------
    int t = within;                    // interleaved stride-64 walk
    if (t >= nt) return;               // (never for 512-block grid; safety)
    int h0, s0;  tile_hs(band, t, h0, s0);

    float4 L[15];
    bool act;
    load_x(h0, s0, L, act);            // in flight during prologue
    decode(h0);
    __syncthreads();
    build_S();
    __syncthreads();
    build_C();
    __syncthreads();

    // ---- pipelined tile loop ----------------------------------------------
    while (true) {
        const int tn    = t + 64;
        const bool more = (tn < nt);
        int hn = h0, sn = s0;
        if (more) tile_hs(band, tn, hn, sn);

        // Phase A: stencil FMA on prefetched registers -> zs
        if (act) {
            const float* Cc = &C[c][0];
            float a0 = 0.f, a1 = 0.f, a2 = 0.f, a3 = 0.f;
            #pragma unroll
            for (int rb = 0; rb < 5; ++rb) {
                const float4 vA = L[rb * 3 + 0];
                const float4 vB = L[rb * 3 + 1];
                const float4 vC = L[rb * 3 + 2];
                const float k0 = Cc[rb * 5 + 0], k1 = Cc[rb * 5 + 1],
                            k2 = Cc[rb * 5 + 2], k3 = Cc[rb * 5 + 3],
                            k4 = Cc[rb * 5 + 4];
                a0 += k0 * vA.z + k1 * vA.w + k2 * vB.x + k3 * vB.y + k4 * vB.z;
                a1 += k0 * vA.w + k1 * vB.x + k2 * vB.y + k3 * vB.z + k4 * vB.w;
                a2 += k0 * vB.x + k1 * vB.y + k2 * vB.z + k3 * vB.w + k4 * vC.x;
                a3 += k0 * vB.y + k1 * vB.z + k2 * vB.w + k3 * vC.x + k4 * vC.y;
            }
            const int p = g * 4;
            zs[p + 0][c] = a0;
            zs[p + 1][c] = a1;
            zs[p + 2][c] = a2;
            zs[p + 3][c] = a3;
        }

        // prefetch next tile's x (registers L free after the FMAs above)
        bool actn = false;
        if (more) load_x(hn, sn, L, actn);

        __syncthreads();                       // zs ready

        // next tile's tap decode: chained global loads hide under GEMV
        if (more) decode(hn);

        // Phase B: 32->64 GEMV for current tile
        {
            const int w0  = s0 * 64;
            const int pxn = (s0 == 5) ? 40 : 64;
            if (j < pxn) {
                float zr[CIN_];
                #pragma unroll
                for (int cc = 0; cc < CIN_; ++cc) zr[cc] = zs[j][cc];
                const float* wp = w_point + oh * 8 * CIN_;   // s_loads
                float* op = out + oh * 8 * HW_ + h0 * W_ + w0 + j;
                #pragma unroll
                for (int oo = 0; oo < 8; ++oo) {
                    float acc = bias[oh * 8 + oo];
                    #pragma unroll
                    for (int cc = 0; cc < CIN_; ++cc)
                        acc += wp[oo * CIN_ + cc] * zr[cc];
                    op[oo * HW_] = acc;        // 256B contiguous per wave
                }
            }
        }

        if (!more) break;

        __syncthreads();                       // T ready; zs consumed
        build_S();
        __syncthreads();                       // S ready
        build_C();
        __syncthreads();                       // C ready for next tile

        t = tn; h0 = hn; s0 = sn; act = actn;
    }
}

extern "C" void kernel_launch(void* const* d_in, const int* in_sizes, int n_in,
                              void* d_out, int out_size, void* d_ws, size_t ws_size,
                              hipStream_t stream) {
    const float* x       = (const float*)d_in[0];
    const float* quad_w  = (const float*)d_in[1];
    const float* vals    = (const float*)d_in[2];
    // d_in[3] = seg  (unused; tap membership implied by entry ordering)
    const int*   hi      = (const int*)d_in[4];
    const int*   wi      = (const int*)d_in[5];
    const float* w_depth = (const float*)d_in[6];
    const float* vals1   = (const float*)d_in[7];
    // d_in[8] = seg1 (unused)
    const int*   hi1     = (const int*)d_in[9];
    const int*   wi1     = (const int*)d_in[10];
    const float* w_point = (const float*)d_in[11];
    const float* bias    = (const float*)d_in[12];
    // d_in[13] = K (compile-time constant 4)

    sepconv_persist<<<512, 512, 0, stream>>>(
        x, quad_w, vals, hi, wi, w_depth, vals1, hi1, wi1,
        w_point, bias, (float*)d_out);
}

// Round 12
// 116.296 us; speedup vs baseline: 1.0145x; 1.0145x over previous
//
#include <hip/hip_runtime.h>

// SepConv on sphere — FINAL (revert to R10, best measured: 116.0 us total).
// Algebra (verified absmax 0.0 since R2): the chain
//   x -> *qw -> DISCO(K=4,9tap) -> depth-mix -> *qw -> DISCO(K=1,4tap) -> 1x1
// composes into one 5x5 clip/wrap stencil with per-(c,h) coefs
// C[c][25] = w_depth[c,:] . S[4][25] (144 composed taps per row), then a
// 32->64 pointwise GEMV. One kernel, one launch.
//
// Structure: 512-thread blocks, one stencil item (4px x 1ch) per thread;
// x float4 loads issued BEFORE the 3-barrier coef prologue (addresses are
// tap-independent, latency drains behind the prologue); XCD band swizzle
// keeps the 5-row halo L2-local (FETCH ~= |x|); GEMV uses wave-uniform
// w_point rows (s_loads) and 256B-contiguous stores.
//
// Tried and rejected with counter evidence: z-roundtrip via ws (R4-R6),
// separate coef kernel (R6-R7: ~1us/launch), fat pipelined blocks (R9:
// VGPR 104 -> occ 12.7%, 69k LDS conflicts, regression), persistent blocks
// (R11: neutral). Kernel-side duration is pinned at ~38-45us across ALL
// structures with VALUBusy 14-16% / HBM 4-6% / 0 conflicts — unattributable
// by available counters; totals are dominated by the ~78us harness reset
// floor (268MB ws re-poison alone measures 43us at 79% HBM peak).

#define H_    181
#define W_    360
#define CIN_  32
#define COUT_ 64
#define K_    4
#define NNZ_  9
#define NNZ1_ 4
#define HW_   (H_*W_)
#define NT_   (NNZ1_*K_*NNZ_)   // 144 composed taps per output row

__global__ __launch_bounds__(512) void sepconv_one(
    const float* __restrict__ x, const float* __restrict__ quad_w,
    const float* __restrict__ vals, const int* __restrict__ hi,
    const int* __restrict__ wi, const float* __restrict__ w_depth,
    const float* __restrict__ vals1, const int* __restrict__ hi1,
    const int* __restrict__ wi1, const float* __restrict__ w_point,
    const float* __restrict__ bias, float* __restrict__ out)
{
    const int bx = blockIdx.x;
    const int h  = (bx & 7) * 23 + (bx >> 3);   // XCD-contiguous row bands
    if (h >= H_) return;                         // 3 pad rows, uniform exit
    const int seg = blockIdx.y;                  // 0..5
    const int w0  = seg * 64;
    const int pxn = (seg == 5) ? 40 : 64;        // 360 = 5*64 + 40
    const int gn  = pxn >> 2;
    const int tid = threadIdx.x;

    __shared__ float Tval[NT_];
    __shared__ int   Tbin[NT_];
    __shared__ float S[K_][25];
    __shared__ float C[CIN_][25];
    __shared__ float zs[64][33];   // [px][ch]; <=2-way banks everywhere (free)

    // --- x prefetch FIRST: addresses independent of taps --------------------
    // thread = (c = tid>>4 in 0..31, g = tid&15): one 4-px stencil item.
    const int g = tid & 15;
    const int c = tid >> 4;
    const bool act = (g < gn);

    int rowoff[5];
    #pragma unroll
    for (int rb = 0; rb < 5; ++rb) {
        int r = h - 2 + rb;
        r = (r < 0) ? 0 : ((r > H_ - 1) ? H_ - 1 : r);
        rowoff[rb] = r * W_;
    }

    const int bw = w0 + g * 4;
    const int cA = (bw + W_ - 4) % W_;
    const int cB = bw;
    const int cC = (bw + 4) % W_;

    float4 L[15];
    if (act) {
        const float* xc = x + c * HW_;
        #pragma unroll
        for (int rb = 0; rb < 5; ++rb) {
            const float* xr = xc + rowoff[rb];
            L[rb * 3 + 0] = *(const float4*)(xr + cA);   // in flight during
            L[rb * 3 + 1] = *(const float4*)(xr + cB);   // the prologue below
            L[rb * 3 + 2] = *(const float4*)(xr + cC);
        }
    }

    // --- coef prologue (parallel; overlaps the x-load drain) ----------------
    if (tid < NT_) {
        const int a   = tid / 36;
        const int rem = tid - a * 36;
        const int k   = rem / 9;
        const int j   = rem - k * 9;
        const int e1  = h * NNZ1_ + a;
        const int m   = hi1[e1];
        const int w1  = wi1[e1];
        const int d1  = (w1 == 1) ? 1 : ((w1 == 0) ? 0 : -1);
        const int e   = (k * H_ + m) * NNZ_ + j;
        const int r   = hi[e];
        const int ww  = wi[e];
        const int d   = (ww == 1) ? 1 : ((ww == 0) ? 0 : -1);
        Tval[tid] = vals1[e1] * quad_w[m] * vals[e] * quad_w[r];
        Tbin[tid] = (r - h + 2) * 5 + (d1 + d + 2);   // in [0,25)
    }
    __syncthreads();

    if (tid < K_ * 25) {           // parallel read-only scans (broadcast LDS)
        const int k   = tid / 25;
        const int bin = tid - k * 25;
        float s = 0.f;
        #pragma unroll
        for (int a = 0; a < NNZ1_; ++a)
            #pragma unroll
            for (int j = 0; j < NNZ_; ++j) {
                const int t2 = a * 36 + k * 9 + j;
                if (Tbin[t2] == bin) s += Tval[t2];
            }
        S[k][bin] = s;
    }
    __syncthreads();

    if (tid < CIN_ * 25) {
        const int cc = tid / 25, bin = tid - cc * 25;
        float acc = 0.f;
        #pragma unroll
        for (int k = 0; k < K_; ++k) acc += w_depth[cc * K_ + k] * S[k][bin];
        C[cc][bin] = acc;
    }
    if (tid + 512 < CIN_ * 25) {
        const int i2 = tid + 512;
        const int cc = i2 / 25, bin = i2 - cc * 25;
        float acc = 0.f;
        #pragma unroll
        for (int k = 0; k < K_; ++k) acc += w_depth[cc * K_ + k] * S[k][bin];
        C[cc][bin] = acc;
    }
    __syncthreads();

    // --- Phase A: FMA on prefetched registers -> LDS z tile -----------------
    if (act) {
        const float* Cc = &C[c][0];
        float a0 = 0.f, a1 = 0.f, a2 = 0.f, a3 = 0.f;
        #pragma unroll
        for (int rb = 0; rb < 5; ++rb) {
            const float4 vA = L[rb * 3 + 0];
            const float4 vB = L[rb * 3 + 1];
            const float4 vC = L[rb * 3 + 2];
            const float k0 = Cc[rb * 5 + 0], k1 = Cc[rb * 5 + 1],
                        k2 = Cc[rb * 5 + 2], k3 = Cc[rb * 5 + 3],
                        k4 = Cc[rb * 5 + 4];
            a0 += k0 * vA.z + k1 * vA.w + k2 * vB.x + k3 * vB.y + k4 * vB.z;
            a1 += k0 * vA.w + k1 * vB.x + k2 * vB.y + k3 * vB.z + k4 * vB.w;
            a2 += k0 * vB.x + k1 * vB.y + k2 * vB.z + k3 * vB.w + k4 * vC.x;
            a3 += k0 * vB.y + k1 * vB.z + k2 * vB.w + k3 * vC.x + k4 * vC.y;
        }
        const int p = g * 4;
        zs[p + 0][c] = a0;      // bank (33(4g+u)+c)%32: <=2-way -> free
        zs[p + 1][c] = a1;
        zs[p + 2][c] = a2;
        zs[p + 3][c] = a3;
    }
    __syncthreads();

    // --- Phase B: 32->64 GEMV; thread = (px j, o-eighth oh) -----------------
    const int j  = tid & 63;
    const int oh = tid >> 6;            // 0..7, wave-uniform
    if (j < pxn) {
        float zr[CIN_];
        #pragma unroll
        for (int cc = 0; cc < CIN_; ++cc) zr[cc] = zs[j][cc];   // 2-way, free

        const float* wp = w_point + oh * 8 * CIN_;              // s_loads
        float* op = out + oh * 8 * HW_ + h * W_ + w0 + j;
        #pragma unroll
        for (int oo = 0; oo < 8; ++oo) {
            float acc = bias[oh * 8 + oo];
            #pragma unroll
            for (int cc = 0; cc < CIN_; ++cc)
                acc += wp[oo * CIN_ + cc] * zr[cc];
            op[oo * HW_] = acc;          // 256B contiguous per wave
        }
    }
}

extern "C" void kernel_launch(void* const* d_in, const int* in_sizes, int n_in,
                              void* d_out, int out_size, void* d_ws, size_t ws_size,
                              hipStream_t stream) {
    const float* x       = (const float*)d_in[0];
    const float* quad_w  = (const float*)d_in[1];
    const float* vals    = (const float*)d_in[2];
    // d_in[3] = seg  (unused; tap membership implied by entry ordering)
    const int*   hi      = (const int*)d_in[4];
    const int*   wi      = (const int*)d_in[5];
    const float* w_depth = (const float*)d_in[6];
    const float* vals1   = (const float*)d_in[7];
    // d_in[8] = seg1 (unused)
    const int*   hi1     = (const int*)d_in[9];
    const int*   wi1     = (const int*)d_in[10];
    const float* w_point = (const float*)d_in[11];
    const float* bias    = (const float*)d_in[12];
    // d_in[13] = K (compile-time constant 4)

    sepconv_one<<<dim3(184, 6), 512, 0, stream>>>(
        x, quad_w, vals, hi, wi, w_depth, vals1, hi1, wi1,
        w_point, bias, (float*)d_out);
}